// Round 12
// baseline (8517.419 us; speedup 1.0000x reference)
//
#include <hip/hip_runtime.h>
#include <math.h>

#define Bsz 64
#define Tn 64
#define Ln 100
#define Lpad 104
#define Dn 128
#define An 18
#define Hn 512
#define NGRP 16

__device__ __forceinline__ float sigf(float x){ return 1.0f/(1.0f+expf(-x)); }

__device__ __forceinline__ void scst(float* p, float v){
  __hip_atomic_store(p, v, __ATOMIC_RELAXED, __HIP_MEMORY_SCOPE_AGENT);
}
__device__ __forceinline__ void scsti(int* p, int v){
  __hip_atomic_store(p, v, __ATOMIC_RELAXED, __HIP_MEMORY_SCOPE_AGENT);
}
__device__ __forceinline__ int lcldi(const int* p){
  return __hip_atomic_load((int*)p, __ATOMIC_RELAXED, __HIP_MEMORY_SCOPE_AGENT);
}

// Hierarchical grid barrier (16 groups, 256B-line-separated counters,
// monotonic phases). Writers drain vmcnt before arrival (__syncthreads
// drains each wave); readers use cached loads of WRITE-ONCE, NON-ALIASED
// addresses -> no cache maintenance needed.
__device__ __forceinline__ void gbar_arrive(int* grp_arr, int* grp_gen, int* root, int nb, int ph){
  const int gs = nb >> 4;
  const int g  = (int)blockIdx.x & 15;
  int a = __hip_atomic_fetch_add(grp_arr + g*64, 1, __ATOMIC_RELAXED, __HIP_MEMORY_SCOPE_AGENT) + 1;
  if (a == ph*gs){
    int r = __hip_atomic_fetch_add(root, 1, __ATOMIC_RELAXED, __HIP_MEMORY_SCOPE_AGENT) + 1;
    if (r == ph*NGRP){
      #pragma unroll
      for (int i = 0; i < NGRP; i++) scsti(grp_gen + i*64, ph);
    }
  }
}
__device__ __forceinline__ void gbar_wait(int* grp_gen, int ph){
  const int g = (int)blockIdx.x & 15;
  while (lcldi(grp_gen + g*64) < ph) __builtin_amdgcn_s_sleep(1);
}
__device__ __forceinline__ void gbarH(int* gA, int* gG, int* gR, int nb, int ph){
  __syncthreads();
  if (threadIdx.x == 0){
    asm volatile("s_waitcnt vmcnt(0) lgkmcnt(0)" ::: "memory");
    gbar_arrive(gA, gG, gR, nb, ph);
    gbar_wait(gG, ph);
  }
  __syncthreads();
}

// ---------- demo transpose: demoT[l][b][d] = demo[0][b][l][d] ----------
__global__ __launch_bounds__(256) void demo_transpose_kernel(
    const float* __restrict__ demo, float* __restrict__ demoT)
{
  int idx = blockIdx.x*256 + threadIdx.x;
  if (idx < Ln*Bsz*Dn) {
    int d = idx & 127;
    int b = (idx >> 7) & 63;
    int l = idx >> 13;
    demoT[idx] = demo[((size_t)(b*Ln + l))*Dn + d];
  }
}

// ---------- generic tiled GEMM: C[M][N] = A[M][K] * B[N][K]^T + bias[n] ----------
__global__ __launch_bounds__(256) void gemm_nt_kernel(
    const float* __restrict__ A, int lda,
    const float* __restrict__ B, int ldb,
    const float* __restrict__ bias,
    float* __restrict__ C, int ldc, int K)
{
  __shared__ float As[64][17];
  __shared__ float Bs[64][17];
  const int m0 = blockIdx.x * 64;
  const int n0 = blockIdx.y * 64;
  const int tx = threadIdx.x & 15;
  const int ty = threadIdx.x >> 4;
  float acc[4][4] = {};
  for (int k0 = 0; k0 < K; k0 += 16) {
    #pragma unroll
    for (int i = 0; i < 4; i++) {
      int e = threadIdx.x + i*256;
      int r = e >> 4, c = e & 15;
      As[r][c] = A[(size_t)(m0 + r)*lda + k0 + c];
      Bs[r][c] = B[(size_t)(n0 + r)*ldb + k0 + c];
    }
    __syncthreads();
    #pragma unroll
    for (int kk = 0; kk < 16; kk++) {
      float a0 = As[ty*4+0][kk], a1 = As[ty*4+1][kk], a2 = As[ty*4+2][kk], a3 = As[ty*4+3][kk];
      float b0 = Bs[tx*4+0][kk], b1 = Bs[tx*4+1][kk], b2 = Bs[tx*4+2][kk], b3 = Bs[tx*4+3][kk];
      acc[0][0] += a0*b0; acc[0][1] += a0*b1; acc[0][2] += a0*b2; acc[0][3] += a0*b3;
      acc[1][0] += a1*b0; acc[1][1] += a1*b1; acc[1][2] += a1*b2; acc[1][3] += a1*b3;
      acc[2][0] += a2*b0; acc[2][1] += a2*b1; acc[2][2] += a2*b2; acc[2][3] += a2*b3;
      acc[3][0] += a3*b0; acc[3][1] += a3*b1; acc[3][2] += a3*b2; acc[3][3] += a3*b3;
    }
    __syncthreads();
  }
  #pragma unroll
  for (int i = 0; i < 4; i++) {
    #pragma unroll
    for (int j = 0; j < 4; j++) {
      int nn = n0 + tx*4 + j;
      float v = acc[i][j] + (bias ? bias[nn] : 0.0f);
      C[(size_t)(m0 + ty*4 + i)*ldc + nn] = v;
    }
  }
}

// ---------- head fold: M2 = out_W @ mid_W; bias2 = out_b + mid_b@out_W^T ----------
__global__ __launch_bounds__(512) void head_fold_kernel(
    const float* __restrict__ mid_W, const float* __restrict__ mid_b,
    const float* __restrict__ out_W, const float* __restrict__ out_b,
    float* __restrict__ M2, float* __restrict__ bias2)
{
  const int a = blockIdx.x;
  const int k = threadIdx.x;
  const float* ow = out_W + (size_t)a*Hn;
  float s = 0.f;
  #pragma unroll 4
  for (int n = 0; n < Hn; n++) s += ow[n]*mid_W[(size_t)n*Hn + k];
  M2[(size_t)a*Hn + k] = s;
  if (k == 0){
    float b2 = out_b[a];
    for (int n = 0; n < Hn; n++) b2 += ow[n]*mid_b[n];
    bias2[a] = b2;
  }
}

// ---------- q head: q[t][b][a] = hhist[t][b] . M2[a] + bias2[a] ----------
__global__ __launch_bounds__(256) void qhead_kernel(
    const float* __restrict__ hhist, const float* __restrict__ M2,
    const float* __restrict__ bias2, float* __restrict__ q)
{
  const int t = blockIdx.x;
  for (int p = threadIdx.x; p < Bsz*An; p += 256){
    int b = p / An, a = p % An;
    const float4* hv = (const float4*)(hhist + ((size_t)t*Bsz + b)*Hn);
    const float4* mv = (const float4*)(M2 + (size_t)a*Hn);
    float s = bias2[a];
    #pragma unroll 8
    for (int k = 0; k < Hn/4; k++){
      float4 H = hv[k], M = mv[k];
      s += H.x*M.x + H.y*M.y + H.z*M.z + H.w*M.w;
    }
    q[((size_t)(t*Bsz + b))*An + a] = s;
  }
}

// ---------- persistent fused encoder: LDS weights, merged pass, batched H ----------
__global__ __launch_bounds__(512, 1) void enc_scan_kernel(
    const float* __restrict__ demoT,   // [Ln][Bsz][Dn]
    const float* __restrict__ Wih, const float* __restrict__ Whh,
    const float* __restrict__ bih, const float* __restrict__ bhh,
    const float* __restrict__ attn_W, const float* __restrict__ attn_b,
    const float* __restrict__ comb_W,
    float* __restrict__ hencR,         // [Ln][Bsz][Hn]  write-once, non-aliased
    float* __restrict__ attnp,         // [Bsz][Ln][Hn]
    float* __restrict__ ceT,           // [Bsz][Hn][Lpad]
    int* __restrict__ gA, int* __restrict__ gG, int* __restrict__ gR)
{
  const int bid  = blockIdx.x;
  const int tid  = threadIdx.x;
  const int lane = tid & 63;
  const int ks   = tid >> 6;          // 0..7
  const int n0   = bid*2;

  __shared__ float lds_whh[8][Hn];
  __shared__ float lds_wih[8][Dn];
  __shared__ float lds_atw[2][Hn];
  __shared__ float lds_cbw[2][Hn];
  __shared__ float red[8][12][Bsz];

  #pragma unroll
  for (int c = 0; c < 2; c++)
    #pragma unroll
    for (int g = 0; g < 4; g++){
      int r = c*4 + g;
      lds_whh[r][tid] = Whh[(size_t)(g*Hn + n0 + c)*Hn + tid];
      if (tid < Dn) lds_wih[r][tid] = Wih[(size_t)(g*Hn + n0 + c)*Dn + tid];
    }
  #pragma unroll
  for (int c = 0; c < 2; c++){
    lds_atw[c][tid] = attn_W[(size_t)(n0 + c)*Hn + tid];
    lds_cbw[c][tid] = comb_W[(size_t)(n0 + c)*(Hn + Dn) + tid];
  }
  float bsum[2][4];
  #pragma unroll
  for (int c = 0; c < 2; c++)
    #pragma unroll
    for (int g = 0; g < 4; g++){
      int r = g*Hn + n0 + c;
      bsum[c][g] = bih[r] + bhh[r];
    }
  const float ab[2] = { attn_b[n0], attn_b[n0+1] };
  float cr[2] = {0.f, 0.f};
  __syncthreads();

  for (int l = 0; l <= Ln; l++){
    float a[2][4] = {{0,0,0,0},{0,0,0,0}};
    float aa[2] = {0,0}, ac[2] = {0,0};
    if (l >= 1){
      const float4* hv = (const float4*)(hencR + ((size_t)(l-1)*Bsz + lane)*Hn) + ks*16;
      float4 H[16];
      #pragma unroll
      for (int q = 0; q < 16; q++) H[q] = hv[q];   // batch loads (MLP vs cold L3)
      #pragma unroll
      for (int q = 0; q < 16; q++){
        #pragma unroll
        for (int c = 0; c < 2; c++){
          #pragma unroll
          for (int g = 0; g < 4; g++){
            float4 W = *(const float4*)&lds_whh[c*4+g][ks*64 + 4*q];
            a[c][g] += H[q].x*W.x + H[q].y*W.y + H[q].z*W.z + H[q].w*W.w;
          }
          float4 Aw = *(const float4*)&lds_atw[c][ks*64 + 4*q];
          aa[c] += H[q].x*Aw.x + H[q].y*Aw.y + H[q].z*Aw.z + H[q].w*Aw.w;
          float4 Cw = *(const float4*)&lds_cbw[c][ks*64 + 4*q];
          ac[c] += H[q].x*Cw.x + H[q].y*Cw.y + H[q].z*Cw.z + H[q].w*Cw.w;
        }
      }
    }
    if (l < Ln){
      const float4* dv = (const float4*)(demoT + ((size_t)l*Bsz + lane)*Dn) + ks*4;
      #pragma unroll
      for (int q = 0; q < 4; q++){
        float4 V = dv[q];
        #pragma unroll
        for (int c = 0; c < 2; c++)
          #pragma unroll
          for (int g = 0; g < 4; g++){
            float4 W = *(const float4*)&lds_wih[c*4+g][ks*16 + 4*q];
            a[c][g] += V.x*W.x + V.y*W.y + V.z*W.z + V.w*W.w;
          }
      }
    }
    #pragma unroll
    for (int c = 0; c < 2; c++){
      #pragma unroll
      for (int g = 0; g < 4; g++) red[ks][c*4+g][lane] = a[c][g];
      red[ks][8+c][lane]  = aa[c];
      red[ks][10+c][lane] = ac[c];
    }
    __syncthreads();
    if (tid < Bsz){
      int b = tid;
      if (l < Ln){
        #pragma unroll
        for (int c = 0; c < 2; c++){
          float g0 = bsum[c][0], g1 = bsum[c][1], g2 = bsum[c][2], g3 = bsum[c][3];
          #pragma unroll
          for (int k = 0; k < 8; k++){
            g0 += red[k][c*4+0][b]; g1 += red[k][c*4+1][b];
            g2 += red[k][c*4+2][b]; g3 += red[k][c*4+3][b];
          }
          float ii = sigf(g0), ff = sigf(g1), gg = tanhf(g2), oo = sigf(g3);
          float cn = ff*cr[c] + ii*gg;
          float hn = oo*tanhf(cn);
          cr[c] = cn;
          scst(hencR + ((size_t)l*Bsz + b)*Hn + n0 + c, hn);
        }
      }
      if (l >= 1){
        #pragma unroll
        for (int c = 0; c < 2; c++){
          float av = ab[c], cv = 0.f;
          #pragma unroll
          for (int k = 0; k < 8; k++){ av += red[k][8+c][b]; cv += red[k][10+c][b]; }
          scst(attnp + ((size_t)(b*Ln + (l-1)))*Hn + n0 + c, av);
          scst(ceT   + ((size_t)(b*Hn + n0 + c))*Lpad + (l-1), cv);
        }
      }
    }
    if (l < Ln) gbarH(gA, gG, gR, (int)gridDim.x, l+1);
  }
}

// ---------- persistent decoder: LDS weights, 2 phases/step, CE_T + batched streams ----------
__global__ __launch_bounds__(512, 1) void dec_scan_kernel(
    const float* __restrict__ h0, const float* __restrict__ c0,
    const float* __restrict__ attnp,   // [Bsz][Ln][Hn]
    const float* __restrict__ ceT,     // [Bsz][Hn][Lpad]
    const float* __restrict__ preobs,  // [Tn*Bsz][Hn]
    const int*   __restrict__ dlen,
    const float* __restrict__ lstm_Wih, const float* __restrict__ lstm_Whh,
    const float* __restrict__ lstm_bih, const float* __restrict__ lstm_bhh,
    const float* __restrict__ comb_b,
    float* __restrict__ xrow,          // [Tn][Bsz][Hn]  write-once, non-aliased
    float* __restrict__ hhist,         // [Tn][Bsz][Hn]  write-once, non-aliased
    float* __restrict__ outp,
    int* __restrict__ gA, int* __restrict__ gG, int* __restrict__ gR)
{
  const int bid  = blockIdx.x;
  const int tid  = threadIdx.x;
  const int lane = tid & 63;
  const int ks   = tid >> 6;          // 0..7
  const int n0   = bid*2;

  __shared__ float lds_wi[8][Hn];
  __shared__ float lds_wh[8][Hn];
  __shared__ __align__(16) float hs[Hn];
  __shared__ __align__(16) float wls[128];
  __shared__ float mx_s, sum_s;
  __shared__ float red[8][8][Bsz];

  #pragma unroll
  for (int c = 0; c < 2; c++)
    #pragma unroll
    for (int g = 0; g < 4; g++){
      int r = c*4 + g;
      lds_wi[r][tid] = lstm_Wih[(size_t)(g*Hn + n0 + c)*Hn + tid];
      lds_wh[r][tid] = lstm_Whh[(size_t)(g*Hn + n0 + c)*Hn + tid];
    }
  float bs[2][4];
  #pragma unroll
  for (int c = 0; c < 2; c++)
    #pragma unroll
    for (int g = 0; g < 4; g++){
      int r = g*Hn + n0 + c;
      bs[c][g] = lstm_bih[r] + lstm_bhh[r];
    }
  float cr[2] = {0.f, 0.f};
  // hoisted: t-invariant attention length for this block's batch
  int len = 0, lenr = 0;
  if (bid < Bsz){ len = dlen[bid]; lenr = (len + 7) & ~7; }  // <= 104 = Lpad
  int ph = 0;
  __syncthreads();

  for (int t = 0; t < Tn; t++){
    const float* hprev_all = (t == 0) ? h0 : (hhist + (size_t)(t-1)*Bsz*Hn);

    // ============ Phase 1: attention (blocks 0..63) + Whh@h partial (ALL) ============
    if (bid < Bsz){
      const int b = bid;
      hs[tid] = hprev_all[(size_t)b*Hn + tid];
      if (tid >= 100 && tid < 128) wls[tid] = -1e30f;
      __syncthreads();
      if (tid < 400){
        int l = tid >> 2, kh = tid & 3;
        const float4* ap = (const float4*)(attnp + ((size_t)(b*Ln + l))*Hn);
        const float4* hv = (const float4*)hs;
        float s = 0.f;
        // kh-rotated index: the 4 kh groups hit distinct LDS bank quartets
        #pragma unroll 8
        for (int k = 0; k < 32; k++){
          int j = kh*32 + ((k + 2*kh) & 31);
          float4 A = ap[j], H = hv[j];
          s += A.x*H.x + A.y*H.y + A.z*H.z + A.w*H.w;
        }
        s += __shfl_xor(s, 1);
        s += __shfl_xor(s, 2);
        if (kh == 0) wls[l] = (l < len) ? s*0.1f : -1e30f;
      }
      __syncthreads();
      if (tid < 64){
        float v = fmaxf(wls[tid], wls[tid+64]);
        for (int off = 1; off < 64; off <<= 1) v = fmaxf(v, __shfl_xor(v, off));
        if (tid == 0) mx_s = v;
      }
      __syncthreads();
      float mx = mx_s;
      if (tid < 64){
        float e0 = (wls[tid]    > -1e29f) ? expf(wls[tid]    - mx) : 0.f;
        float e1 = (wls[tid+64] > -1e29f) ? expf(wls[tid+64] - mx) : 0.f;
        wls[tid] = e0; wls[tid+64] = e1;   // exact 0.0 beyond len (incl. 100..127)
        float v = e0 + e1;
        for (int off = 1; off < 64; off <<= 1) v += __shfl_xor(v, off);
        if (tid == 0) sum_s = v;
      }
      __syncthreads();
      float inv = 1.0f / sum_s;
      {
        int n = tid;
        const float4* cb4 = (const float4*)(ceT + ((size_t)b*Hn + n)*Lpad);
        float acc = 0.f;
        int l4 = lenr >> 2;
        #pragma unroll 4
        for (int j = 0; j < l4; ++j){
          float4 C4 = cb4[j];
          float4 W4 = *(const float4*)&wls[4*j];   // broadcast; zeros pad beyond len
          acc += C4.x*W4.x + C4.y*W4.y + C4.z*W4.z + C4.w*W4.w;
        }
        float v = acc*inv + preobs[((size_t)(t*Bsz + b))*Hn + n] + comb_b[n];
        scst(xrow + ((size_t)t*Bsz + b)*Hn + n, fmaxf(v, 0.f));
      }
    }
    // all blocks: Whh @ h(t-1) partial for own 2 columns; kept in VGPRs across barrier
    float hpa[2][4] = {{0,0,0,0},{0,0,0,0}};
    {
      const float4* hv = (const float4*)(hprev_all + (size_t)lane*Hn) + ks*16;
      float4 H[16];
      #pragma unroll
      for (int q = 0; q < 16; q++) H[q] = hv[q];
      #pragma unroll
      for (int q = 0; q < 16; q++){
        #pragma unroll
        for (int c = 0; c < 2; c++)
          #pragma unroll
          for (int g = 0; g < 4; g++){
            float4 W = *(const float4*)&lds_wh[c*4+g][ks*64 + 4*q];
            hpa[c][g] += H[q].x*W.x + H[q].y*W.y + H[q].z*W.z + H[q].w*W.w;
          }
      }
    }
    gbarH(gA, gG, gR, (int)gridDim.x, ++ph);

    // ============ Phase 2: += Wih@x; reduce; cell ============
    {
      const float4* xv = (const float4*)(xrow + ((size_t)t*Bsz + lane)*Hn) + ks*16;
      float4 X[16];
      #pragma unroll
      for (int q = 0; q < 16; q++) X[q] = xv[q];
      #pragma unroll
      for (int q = 0; q < 16; q++){
        #pragma unroll
        for (int c = 0; c < 2; c++)
          #pragma unroll
          for (int g = 0; g < 4; g++){
            float4 W = *(const float4*)&lds_wi[c*4+g][ks*64 + 4*q];
            hpa[c][g] += X[q].x*W.x + X[q].y*W.y + X[q].z*W.z + X[q].w*W.w;
          }
      }
      #pragma unroll
      for (int c = 0; c < 2; c++)
        #pragma unroll
        for (int g = 0; g < 4; g++) red[ks][c*4+g][lane] = hpa[c][g];
      __syncthreads();
      if (tid < Bsz){
        int b = tid;
        #pragma unroll
        for (int c = 0; c < 2; c++){
          int n = n0 + c;
          if (t == 0) cr[c] = c0[(size_t)b*Hn + n];
          float g0 = bs[c][0], g1 = bs[c][1], g2 = bs[c][2], g3 = bs[c][3];
          #pragma unroll
          for (int k = 0; k < 8; k++){
            g0 += red[k][c*4+0][b]; g1 += red[k][c*4+1][b];
            g2 += red[k][c*4+2][b]; g3 += red[k][c*4+3][b];
          }
          float ii = sigf(g0), ff = sigf(g1), gg = tanhf(g2), oo = sigf(g3);
          float cn = ff*cr[c] + ii*gg;
          float hn = oo*tanhf(cn);
          cr[c] = cn;
          scst(hhist + ((size_t)t*Bsz + b)*Hn + n, hn);
          if (t == Tn - 1){
            outp[Tn*Bsz*An + (size_t)b*Hn + n]           = hn;
            outp[Tn*Bsz*An + Bsz*Hn + (size_t)b*Hn + n]  = cn;
          }
        }
      }
    }
    if (t < Tn - 1) gbarH(gA, gG, gR, (int)gridDim.x, ++ph);
  }
}

extern "C" void kernel_launch(void* const* d_in, const int* in_sizes, int n_in,
                              void* d_out, int out_size, void* d_ws, size_t ws_size,
                              hipStream_t stream) {
  (void)in_sizes; (void)n_in; (void)out_size; (void)ws_size;
  const float* state    = (const float*)d_in[0];
  const float* demo     = (const float*)d_in[1];
  const int*   dlen     = (const int*)  d_in[2];
  const float* h0       = (const float*)d_in[5];
  const float* c0       = (const float*)d_in[6];
  const float* enc_Wih  = (const float*)d_in[7];
  const float* enc_Whh  = (const float*)d_in[8];
  const float* enc_bih  = (const float*)d_in[9];
  const float* enc_bhh  = (const float*)d_in[10];
  const float* attn_W   = (const float*)d_in[11];
  const float* attn_b   = (const float*)d_in[12];
  const float* comb_W   = (const float*)d_in[13];
  const float* comb_b   = (const float*)d_in[14];
  const float* lstm_Wih = (const float*)d_in[15];
  const float* lstm_Whh = (const float*)d_in[16];
  const float* lstm_bih = (const float*)d_in[17];
  const float* lstm_bhh = (const float*)d_in[18];
  const float* mid_W    = (const float*)d_in[19];
  const float* mid_b    = (const float*)d_in[20];
  const float* out_W    = (const float*)d_in[21];
  const float* out_b    = (const float*)d_in[22];
  float* ws   = (float*)d_ws;
  float* qout = (float*)d_out;

  // NON-ALIASED workspace layout (f32 words) — ~65.2 MiB total.
  float* attnp  = ws + 0;          // 3,276,800   [B][L][H]
  float* ceT    = ws + 3276800;    // 3,407,872   [B][H][Lpad]
  float* preobs = ws + 6684672;    // 2,097,152   [T*B][H]
  float* demoT  = ws + 8781824;    //   819,200   [L][B][D]
  float* hencR  = ws + 9601024;    // 3,276,800   [L][B][H]
  float* xrow   = ws + 12877824;   // 2,097,152   [T][B][H]
  float* hhist  = ws + 14974976;   // 2,097,152   [T][B][H]
  int*   barB   = (int*)(ws + 17072128);  // 4,224 ints
  int* encA = barB;          int* encG = barB + 1024; int* encR = barB + 2048;
  int* decA = barB + 2112;   int* decG = barB + 3136; int* decR = barB + 4160;
  float* M2    = ws + 17076352;    // 9,216  [An][Hn]
  float* bias2 = ws + 17085568;    // 64

  hipMemsetAsync((void*)barB, 0, 4224*4, stream);

  demo_transpose_kernel<<<3200, 256, 0, stream>>>(demo, demoT);

  head_fold_kernel<<<An, 512, 0, stream>>>(mid_W, mid_b, out_W, out_b, M2, bias2);

  // preobs[(t,b)][n] = state[t,b,:] . comb_W[n, 512:640]
  gemm_nt_kernel<<<dim3(Tn*Bsz/64, Hn/64), 256, 0, stream>>>(
      state, Dn, comb_W + Hn, Hn + Dn, nullptr, preobs, Hn, Dn);

  enc_scan_kernel<<<256, 512, 0, stream>>>(
      demoT, enc_Wih, enc_Whh, enc_bih, enc_bhh, attn_W, attn_b, comb_W,
      hencR, attnp, ceT, encA, encG, encR);

  dec_scan_kernel<<<256, 512, 0, stream>>>(
      h0, c0, attnp, ceT, preobs, dlen, lstm_Wih, lstm_Whh, lstm_bih, lstm_bhh,
      comb_b, xrow, hhist, qout, decA, decG, decR);

  // q = hhist @ M2^T + bias2
  qhead_kernel<<<Tn, 256, 0, stream>>>(hhist, M2, bias2, qout);
}

// Round 13
// 2960.178 us; speedup vs baseline: 2.8773x; 2.8773x over previous
//
#include <hip/hip_runtime.h>
#include <math.h>

#define Bsz 64
#define Tn 64
#define Ln 100
#define Dn 128
#define An 18
#define Hn 512
#define NGRP 16

__device__ __forceinline__ float sigf(float x){ return 1.0f/(1.0f+expf(-x)); }

__device__ __forceinline__ void scst(float* p, float v){
  __hip_atomic_store(p, v, __ATOMIC_RELAXED, __HIP_MEMORY_SCOPE_AGENT);
}
__device__ __forceinline__ void scsti(int* p, int v){
  __hip_atomic_store(p, v, __ATOMIC_RELAXED, __HIP_MEMORY_SCOPE_AGENT);
}
__device__ __forceinline__ int lcldi(const int* p){
  return __hip_atomic_load((int*)p, __ATOMIC_RELAXED, __HIP_MEMORY_SCOPE_AGENT);
}

// Hierarchical grid barrier (16 groups x 16 blocks, 256B-line-separated
// counters, monotonic phases). Writers drain vmcnt before arrival
// (__syncthreads drains each wave); readers use cached loads of WRITE-ONCE,
// NON-ALIASED addresses -> no cache maintenance needed.
__device__ __forceinline__ void gbar_arrive(int* grp_arr, int* grp_gen, int* root, int nb, int ph){
  const int gs = nb >> 4;
  const int g  = (int)blockIdx.x & 15;
  int a = __hip_atomic_fetch_add(grp_arr + g*64, 1, __ATOMIC_RELAXED, __HIP_MEMORY_SCOPE_AGENT) + 1;
  if (a == ph*gs){
    int r = __hip_atomic_fetch_add(root, 1, __ATOMIC_RELAXED, __HIP_MEMORY_SCOPE_AGENT) + 1;
    if (r == ph*NGRP){
      #pragma unroll
      for (int i = 0; i < NGRP; i++) scsti(grp_gen + i*64, ph);
    }
  }
}
__device__ __forceinline__ void gbar_wait(int* grp_gen, int ph){
  const int g = (int)blockIdx.x & 15;
  while (lcldi(grp_gen + g*64) < ph) __builtin_amdgcn_s_sleep(1);
}
__device__ __forceinline__ void gbarH(int* gA, int* gG, int* gR, int nb, int ph){
  __syncthreads();
  if (threadIdx.x == 0){
    asm volatile("s_waitcnt vmcnt(0) lgkmcnt(0)" ::: "memory");
    gbar_arrive(gA, gG, gR, nb, ph);
    gbar_wait(gG, ph);
  }
  __syncthreads();
}

// ---------- demo transpose: demoT[l][b][d] = demo[0][b][l][d] ----------
__global__ __launch_bounds__(256) void demo_transpose_kernel(
    const float* __restrict__ demo, float* __restrict__ demoT)
{
  int idx = blockIdx.x*256 + threadIdx.x;
  if (idx < Ln*Bsz*Dn) {
    int d = idx & 127;
    int b = (idx >> 7) & 63;
    int l = idx >> 13;
    demoT[idx] = demo[((size_t)(b*Ln + l))*Dn + d];
  }
}

// ---------- generic tiled GEMM: C[M][N] = A[M][K] * B[N][K]^T + bias[n] ----------
__global__ __launch_bounds__(256) void gemm_nt_kernel(
    const float* __restrict__ A, int lda,
    const float* __restrict__ B, int ldb,
    const float* __restrict__ bias,
    float* __restrict__ C, int ldc, int K)
{
  __shared__ float As[64][17];
  __shared__ float Bs[64][17];
  const int m0 = blockIdx.x * 64;
  const int n0 = blockIdx.y * 64;
  const int tx = threadIdx.x & 15;
  const int ty = threadIdx.x >> 4;
  float acc[4][4] = {};
  for (int k0 = 0; k0 < K; k0 += 16) {
    #pragma unroll
    for (int i = 0; i < 4; i++) {
      int e = threadIdx.x + i*256;
      int r = e >> 4, c = e & 15;
      As[r][c] = A[(size_t)(m0 + r)*lda + k0 + c];
      Bs[r][c] = B[(size_t)(n0 + r)*ldb + k0 + c];
    }
    __syncthreads();
    #pragma unroll
    for (int kk = 0; kk < 16; kk++) {
      float a0 = As[ty*4+0][kk], a1 = As[ty*4+1][kk], a2 = As[ty*4+2][kk], a3 = As[ty*4+3][kk];
      float b0 = Bs[tx*4+0][kk], b1 = Bs[tx*4+1][kk], b2 = Bs[tx*4+2][kk], b3 = Bs[tx*4+3][kk];
      acc[0][0] += a0*b0; acc[0][1] += a0*b1; acc[0][2] += a0*b2; acc[0][3] += a0*b3;
      acc[1][0] += a1*b0; acc[1][1] += a1*b1; acc[1][2] += a1*b2; acc[1][3] += a1*b3;
      acc[2][0] += a2*b0; acc[2][1] += a2*b1; acc[2][2] += a2*b2; acc[2][3] += a2*b3;
      acc[3][0] += a3*b0; acc[3][1] += a3*b1; acc[3][2] += a3*b2; acc[3][3] += a3*b3;
    }
    __syncthreads();
  }
  #pragma unroll
  for (int i = 0; i < 4; i++) {
    #pragma unroll
    for (int j = 0; j < 4; j++) {
      int nn = n0 + tx*4 + j;
      float v = acc[i][j] + (bias ? bias[nn] : 0.0f);
      C[(size_t)(m0 + ty*4 + i)*ldc + nn] = v;
    }
  }
}

// ---------- head fold: M2 = out_W @ mid_W; bias2 = out_b + mid_b@out_W^T ----------
__global__ __launch_bounds__(512) void head_fold_kernel(
    const float* __restrict__ mid_W, const float* __restrict__ mid_b,
    const float* __restrict__ out_W, const float* __restrict__ out_b,
    float* __restrict__ M2, float* __restrict__ bias2)
{
  const int a = blockIdx.x;
  const int k = threadIdx.x;
  const float* ow = out_W + (size_t)a*Hn;
  float s = 0.f;
  #pragma unroll 4
  for (int n = 0; n < Hn; n++) s += ow[n]*mid_W[(size_t)n*Hn + k];
  M2[(size_t)a*Hn + k] = s;
  if (k == 0){
    float b2 = out_b[a];
    for (int n = 0; n < Hn; n++) b2 += ow[n]*mid_b[n];
    bias2[a] = b2;
  }
}

// ---------- q head: q[t][b][a] = hhist[t][b] . M2[a] + bias2[a] ----------
__global__ __launch_bounds__(256) void qhead_kernel(
    const float* __restrict__ hhist, const float* __restrict__ M2,
    const float* __restrict__ bias2, float* __restrict__ q)
{
  const int t = blockIdx.x;
  for (int p = threadIdx.x; p < Bsz*An; p += 256){
    int b = p / An, a = p % An;
    const float4* hv = (const float4*)(hhist + ((size_t)t*Bsz + b)*Hn);
    const float4* mv = (const float4*)(M2 + (size_t)a*Hn);
    float s = bias2[a];
    #pragma unroll 8
    for (int k = 0; k < Hn/4; k++){
      float4 H = hv[k], M = mv[k];
      s += H.x*M.x + H.y*M.y + H.z*M.z + H.w*M.w;
    }
    q[((size_t)(t*Bsz + b))*An + a] = s;
  }
}

// ---------- persistent fused encoder: LDS weights, merged pass ----------
__global__ __launch_bounds__(512, 1) void enc_scan_kernel(
    const float* __restrict__ demoT,   // [Ln][Bsz][Dn]
    const float* __restrict__ Wih, const float* __restrict__ Whh,
    const float* __restrict__ bih, const float* __restrict__ bhh,
    const float* __restrict__ attn_W, const float* __restrict__ attn_b,
    const float* __restrict__ comb_W,
    float* __restrict__ hencR,         // [Ln][Bsz][Hn]  write-once, non-aliased
    float* __restrict__ attnp,         // [Bsz][Ln][Hn]
    float* __restrict__ CE,            // [Bsz][Ln][Hn] (+pad)
    int* __restrict__ gA, int* __restrict__ gG, int* __restrict__ gR)
{
  const int bid  = blockIdx.x;
  const int tid  = threadIdx.x;
  const int lane = tid & 63;
  const int ks   = tid >> 6;          // 0..7
  const int n0   = bid*2;

  __shared__ float lds_whh[8][Hn];
  __shared__ float lds_wih[8][Dn];
  __shared__ float lds_atw[2][Hn];
  __shared__ float lds_cbw[2][Hn];
  __shared__ float red[8][12][Bsz];

  #pragma unroll
  for (int c = 0; c < 2; c++)
    #pragma unroll
    for (int g = 0; g < 4; g++){
      int r = c*4 + g;
      lds_whh[r][tid] = Whh[(size_t)(g*Hn + n0 + c)*Hn + tid];
      if (tid < Dn) lds_wih[r][tid] = Wih[(size_t)(g*Hn + n0 + c)*Dn + tid];
    }
  #pragma unroll
  for (int c = 0; c < 2; c++){
    lds_atw[c][tid] = attn_W[(size_t)(n0 + c)*Hn + tid];
    lds_cbw[c][tid] = comb_W[(size_t)(n0 + c)*(Hn + Dn) + tid];
  }
  float bsum[2][4];
  #pragma unroll
  for (int c = 0; c < 2; c++)
    #pragma unroll
    for (int g = 0; g < 4; g++){
      int r = g*Hn + n0 + c;
      bsum[c][g] = bih[r] + bhh[r];
    }
  const float ab[2] = { attn_b[n0], attn_b[n0+1] };
  float cr[2] = {0.f, 0.f};
  __syncthreads();

  for (int l = 0; l <= Ln; l++){
    float a[2][4] = {{0,0,0,0},{0,0,0,0}};
    float aa[2] = {0,0}, ac[2] = {0,0};
    if (l >= 1){
      const float4* hv = (const float4*)(hencR + ((size_t)(l-1)*Bsz + lane)*Hn) + ks*16;
      #pragma unroll 4
      for (int q = 0; q < 16; q++){
        float4 H = hv[q];
        #pragma unroll
        for (int c = 0; c < 2; c++){
          #pragma unroll
          for (int g = 0; g < 4; g++){
            float4 W = *(const float4*)&lds_whh[c*4+g][ks*64 + 4*q];
            a[c][g] += H.x*W.x + H.y*W.y + H.z*W.z + H.w*W.w;
          }
          float4 Aw = *(const float4*)&lds_atw[c][ks*64 + 4*q];
          aa[c] += H.x*Aw.x + H.y*Aw.y + H.z*Aw.z + H.w*Aw.w;
          float4 Cw = *(const float4*)&lds_cbw[c][ks*64 + 4*q];
          ac[c] += H.x*Cw.x + H.y*Cw.y + H.z*Cw.z + H.w*Cw.w;
        }
      }
    }
    if (l < Ln){
      const float4* dv = (const float4*)(demoT + ((size_t)l*Bsz + lane)*Dn) + ks*4;
      #pragma unroll
      for (int q = 0; q < 4; q++){
        float4 V = dv[q];
        #pragma unroll
        for (int c = 0; c < 2; c++)
          #pragma unroll
          for (int g = 0; g < 4; g++){
            float4 W = *(const float4*)&lds_wih[c*4+g][ks*16 + 4*q];
            a[c][g] += V.x*W.x + V.y*W.y + V.z*W.z + V.w*W.w;
          }
      }
    }
    #pragma unroll
    for (int c = 0; c < 2; c++){
      #pragma unroll
      for (int g = 0; g < 4; g++) red[ks][c*4+g][lane] = a[c][g];
      red[ks][8+c][lane]  = aa[c];
      red[ks][10+c][lane] = ac[c];
    }
    __syncthreads();
    if (tid < Bsz){
      int b = tid;
      if (l < Ln){
        #pragma unroll
        for (int c = 0; c < 2; c++){
          float g0 = bsum[c][0], g1 = bsum[c][1], g2 = bsum[c][2], g3 = bsum[c][3];
          #pragma unroll
          for (int k = 0; k < 8; k++){
            g0 += red[k][c*4+0][b]; g1 += red[k][c*4+1][b];
            g2 += red[k][c*4+2][b]; g3 += red[k][c*4+3][b];
          }
          float ii = sigf(g0), ff = sigf(g1), gg = tanhf(g2), oo = sigf(g3);
          float cn = ff*cr[c] + ii*gg;
          float hn = oo*tanhf(cn);
          cr[c] = cn;
          scst(hencR + ((size_t)l*Bsz + b)*Hn + n0 + c, hn);
        }
      }
      if (l >= 1){
        #pragma unroll
        for (int c = 0; c < 2; c++){
          float av = ab[c], cv = 0.f;
          #pragma unroll
          for (int k = 0; k < 8; k++){ av += red[k][8+c][b]; cv += red[k][10+c][b]; }
          scst(attnp + ((size_t)(b*Ln + (l-1)))*Hn + n0 + c, av);
          scst(CE    + ((size_t)(b*Ln + (l-1)))*Hn + n0 + c, cv);
        }
      }
    }
    if (l < Ln) gbarH(gA, gG, gR, (int)gridDim.x, l+1);
  }
}

// ---------- persistent decoder: LDS weights, 2 phases/step ----------
__global__ __launch_bounds__(512, 1) void dec_scan_kernel(
    const float* __restrict__ h0, const float* __restrict__ c0,
    const float* __restrict__ attnp,   // [Bsz][Ln][Hn]
    const float* __restrict__ CE,      // [Bsz][Ln][Hn] (+pad, over-read x0 safe)
    const float* __restrict__ preobs,  // [Tn*Bsz][Hn]
    const int*   __restrict__ dlen,
    const float* __restrict__ lstm_Wih, const float* __restrict__ lstm_Whh,
    const float* __restrict__ lstm_bih, const float* __restrict__ lstm_bhh,
    const float* __restrict__ comb_b,
    float* __restrict__ xrow,          // [Tn][Bsz][Hn]  write-once, non-aliased
    float* __restrict__ hhist,         // [Tn][Bsz][Hn]  write-once, non-aliased
    float* __restrict__ outp,
    int* __restrict__ gA, int* __restrict__ gG, int* __restrict__ gR)
{
  const int bid  = blockIdx.x;
  const int tid  = threadIdx.x;
  const int lane = tid & 63;
  const int ks   = tid >> 6;          // 0..7
  const int n0   = bid*2;

  __shared__ float lds_wi[8][Hn];
  __shared__ float lds_wh[8][Hn];
  __shared__ __align__(16) float hs[Hn];
  __shared__ __align__(16) float wls[128];
  __shared__ float mx_s, sum_s;
  __shared__ float red[8][8][Bsz];

  #pragma unroll
  for (int c = 0; c < 2; c++)
    #pragma unroll
    for (int g = 0; g < 4; g++){
      int r = c*4 + g;
      lds_wi[r][tid] = lstm_Wih[(size_t)(g*Hn + n0 + c)*Hn + tid];
      lds_wh[r][tid] = lstm_Whh[(size_t)(g*Hn + n0 + c)*Hn + tid];
    }
  float bs[2][4];
  #pragma unroll
  for (int c = 0; c < 2; c++)
    #pragma unroll
    for (int g = 0; g < 4; g++){
      int r = g*Hn + n0 + c;
      bs[c][g] = lstm_bih[r] + lstm_bhh[r];
    }
  float cr[2] = {0.f, 0.f};
  // hoisted: t-invariant attention length for this block's batch
  int len = 0, lenr = 0;
  if (bid < Bsz){ len = dlen[bid]; lenr = (len + 7) & ~7; }
  int ph = 0;
  __syncthreads();

  for (int t = 0; t < Tn; t++){
    const float* hprev_all = (t == 0) ? h0 : (hhist + (size_t)(t-1)*Bsz*Hn);

    // ============ Phase 1: attention (blocks 0..63) + Whh@h partial (ALL) ============
    if (bid < Bsz){
      const int b = bid;
      hs[tid] = hprev_all[(size_t)b*Hn + tid];
      if (tid >= 100 && tid < 128) wls[tid] = -1e30f;
      __syncthreads();
      if (tid < 400){
        int l = tid >> 2, kh = tid & 3;
        const float4* ap = (const float4*)(attnp + ((size_t)(b*Ln + l))*Hn);
        const float4* hv = (const float4*)hs;
        float s = 0.f;
        // kh-rotated index: the 4 kh groups hit distinct LDS bank quartets
        // (same permutation on both operands -> identical dot product)
        #pragma unroll 8
        for (int k = 0; k < 32; k++){
          int j = kh*32 + ((k + 2*kh) & 31);
          float4 A = ap[j], H = hv[j];
          s += A.x*H.x + A.y*H.y + A.z*H.z + A.w*H.w;
        }
        s += __shfl_xor(s, 1);
        s += __shfl_xor(s, 2);
        if (kh == 0) wls[l] = (l < len) ? s*0.1f : -1e30f;
      }
      __syncthreads();
      if (tid < 64){
        float v = fmaxf(wls[tid], wls[tid+64]);
        for (int off = 1; off < 64; off <<= 1) v = fmaxf(v, __shfl_xor(v, off));
        if (tid == 0) mx_s = v;
      }
      __syncthreads();
      float mx = mx_s;
      if (tid < 64){
        float e0 = (wls[tid]    > -1e29f) ? expf(wls[tid]    - mx) : 0.f;
        float e1 = (wls[tid+64] > -1e29f) ? expf(wls[tid+64] - mx) : 0.f;
        wls[tid] = e0; wls[tid+64] = e1;   // exact 0.0 beyond len (incl. 100..127)
        float v = e0 + e1;
        for (int off = 1; off < 64; off <<= 1) v += __shfl_xor(v, off);
        if (tid == 0) sum_s = v;
      }
      __syncthreads();
      float inv = 1.0f / sum_s;
      {
        int n = tid;
        const float* cb = CE + (size_t)b*Ln*Hn + n;
        float acc = 0.f;
        #pragma unroll 8
        for (int l2 = 0; l2 < lenr; ++l2) acc += cb[(size_t)l2*Hn]*wls[l2]; // wls==0 pads
        float v = acc*inv + preobs[((size_t)(t*Bsz + b))*Hn + n] + comb_b[n];
        scst(xrow + ((size_t)t*Bsz + b)*Hn + n, fmaxf(v, 0.f));
      }
    }
    // all blocks: Whh @ h(t-1) partial for own 2 columns; kept in VGPRs across barrier
    float hpa[2][4] = {{0,0,0,0},{0,0,0,0}};
    {
      const float4* hv = (const float4*)(hprev_all + (size_t)lane*Hn) + ks*16;
      #pragma unroll 4
      for (int q = 0; q < 16; q++){
        float4 H = hv[q];
        #pragma unroll
        for (int c = 0; c < 2; c++)
          #pragma unroll
          for (int g = 0; g < 4; g++){
            float4 W = *(const float4*)&lds_wh[c*4+g][ks*64 + 4*q];
            hpa[c][g] += H.x*W.x + H.y*W.y + H.z*W.z + H.w*W.w;
          }
      }
    }
    gbarH(gA, gG, gR, (int)gridDim.x, ++ph);

    // ============ Phase 2: += Wih@x; reduce; cell ============
    {
      const float4* xv = (const float4*)(xrow + ((size_t)t*Bsz + lane)*Hn) + ks*16;
      #pragma unroll 4
      for (int q = 0; q < 16; q++){
        float4 X = xv[q];
        #pragma unroll
        for (int c = 0; c < 2; c++)
          #pragma unroll
          for (int g = 0; g < 4; g++){
            float4 W = *(const float4*)&lds_wi[c*4+g][ks*64 + 4*q];
            hpa[c][g] += X.x*W.x + X.y*W.y + X.z*W.z + X.w*W.w;
          }
      }
      #pragma unroll
      for (int c = 0; c < 2; c++)
        #pragma unroll
        for (int g = 0; g < 4; g++) red[ks][c*4+g][lane] = hpa[c][g];
      __syncthreads();
      if (tid < Bsz){
        int b = tid;
        #pragma unroll
        for (int c = 0; c < 2; c++){
          int n = n0 + c;
          if (t == 0) cr[c] = c0[(size_t)b*Hn + n];
          float g0 = bs[c][0], g1 = bs[c][1], g2 = bs[c][2], g3 = bs[c][3];
          #pragma unroll
          for (int k = 0; k < 8; k++){
            g0 += red[k][c*4+0][b]; g1 += red[k][c*4+1][b];
            g2 += red[k][c*4+2][b]; g3 += red[k][c*4+3][b];
          }
          float ii = sigf(g0), ff = sigf(g1), gg = tanhf(g2), oo = sigf(g3);
          float cn = ff*cr[c] + ii*gg;
          float hn = oo*tanhf(cn);
          cr[c] = cn;
          scst(hhist + ((size_t)t*Bsz + b)*Hn + n, hn);
          if (t == Tn - 1){
            outp[Tn*Bsz*An + (size_t)b*Hn + n]           = hn;
            outp[Tn*Bsz*An + Bsz*Hn + (size_t)b*Hn + n]  = cn;
          }
        }
      }
    }
    if (t < Tn - 1) gbarH(gA, gG, gR, (int)gridDim.x, ++ph);
  }
}

extern "C" void kernel_launch(void* const* d_in, const int* in_sizes, int n_in,
                              void* d_out, int out_size, void* d_ws, size_t ws_size,
                              hipStream_t stream) {
  (void)in_sizes; (void)n_in; (void)out_size; (void)ws_size;
  const float* state    = (const float*)d_in[0];
  const float* demo     = (const float*)d_in[1];
  const int*   dlen     = (const int*)  d_in[2];
  const float* h0       = (const float*)d_in[5];
  const float* c0       = (const float*)d_in[6];
  const float* enc_Wih  = (const float*)d_in[7];
  const float* enc_Whh  = (const float*)d_in[8];
  const float* enc_bih  = (const float*)d_in[9];
  const float* enc_bhh  = (const float*)d_in[10];
  const float* attn_W   = (const float*)d_in[11];
  const float* attn_b   = (const float*)d_in[12];
  const float* comb_W   = (const float*)d_in[13];
  const float* comb_b   = (const float*)d_in[14];
  const float* lstm_Wih = (const float*)d_in[15];
  const float* lstm_Whh = (const float*)d_in[16];
  const float* lstm_bih = (const float*)d_in[17];
  const float* lstm_bhh = (const float*)d_in[18];
  const float* mid_W    = (const float*)d_in[19];
  const float* mid_b    = (const float*)d_in[20];
  const float* out_W    = (const float*)d_in[21];
  const float* out_b    = (const float*)d_in[22];
  float* ws   = (float*)d_ws;
  float* qout = (float*)d_out;

  // NON-ALIASED workspace layout (f32 words) — ~64.7 MiB total.
  float* attnp  = ws + 0;          // 3,276,800   [B][L][H]
  float* CE     = ws + 3276800;    // 3,276,800 + 2048 pad (lenr over-read)
  float* preobs = ws + 6555648;    // 2,097,152   [T*B][H]
  float* demoT  = ws + 8652800;    //   819,200   [L][B][D]
  float* hencR  = ws + 9472000;    // 3,276,800   [L][B][H]
  float* xrow   = ws + 12748800;   // 2,097,152   [T][B][H]
  float* hhist  = ws + 14845952;   // 2,097,152   [T][B][H]
  int*   barB   = (int*)(ws + 16943104);  // 4,224 ints
  int* encA = barB;          int* encG = barB + 1024; int* encR = barB + 2048;
  int* decA = barB + 2112;   int* decG = barB + 3136; int* decR = barB + 4160;
  float* M2    = ws + 16947328;    // 9,216  [An][Hn]
  float* bias2 = ws + 16956544;    // 64

  hipMemsetAsync((void*)barB, 0, 4224*4, stream);

  demo_transpose_kernel<<<3200, 256, 0, stream>>>(demo, demoT);

  head_fold_kernel<<<An, 512, 0, stream>>>(mid_W, mid_b, out_W, out_b, M2, bias2);

  // preobs[(t,b)][n] = state[t,b,:] . comb_W[n, 512:640]
  gemm_nt_kernel<<<dim3(Tn*Bsz/64, Hn/64), 256, 0, stream>>>(
      state, Dn, comb_W + Hn, Hn + Dn, nullptr, preobs, Hn, Dn);

  enc_scan_kernel<<<256, 512, 0, stream>>>(
      demoT, enc_Wih, enc_Whh, enc_bih, enc_bhh, attn_W, attn_b, comb_W,
      hencR, attnp, CE, encA, encG, encR);

  dec_scan_kernel<<<256, 512, 0, stream>>>(
      h0, c0, attnp, CE, preobs, dlen, lstm_Wih, lstm_Whh, lstm_bih, lstm_bhh,
      comb_b, xrow, hhist, qout, decA, decG, decR);

  // q = hhist @ M2^T + bias2
  qhead_kernel<<<Tn, 256, 0, stream>>>(hhist, M2, bias2, qout);
}

// Round 15
// 2823.118 us; speedup vs baseline: 3.0170x; 1.0485x over previous
//
#include <hip/hip_runtime.h>
#include <math.h>

#define Bsz 64
#define Tn 64
#define Ln 100
#define Dn 128
#define An 18
#define Hn 512
#define NGRP 16

__device__ __forceinline__ float sigf(float x){ return 1.0f/(1.0f+expf(-x)); }

__device__ __forceinline__ void scst(float* p, float v){
  __hip_atomic_store(p, v, __ATOMIC_RELAXED, __HIP_MEMORY_SCOPE_AGENT);
}
__device__ __forceinline__ void scsti(int* p, int v){
  __hip_atomic_store(p, v, __ATOMIC_RELAXED, __HIP_MEMORY_SCOPE_AGENT);
}
__device__ __forceinline__ int lcldi(const int* p){
  return __hip_atomic_load((int*)p, __ATOMIC_RELAXED, __HIP_MEMORY_SCOPE_AGENT);
}

// Hierarchical grid barrier (16 groups x 16 blocks, 256B-line-separated
// counters, monotonic phases). Writers drain vmcnt before arrival
// (__syncthreads emits s_waitcnt vmcnt(0) per wave); readers use cached
// loads of WRITE-ONCE, NON-ALIASED addresses -> no cache maintenance.
__device__ __forceinline__ void gbar_arrive(int* grp_arr, int* grp_gen, int* root, int nb, int ph){
  const int gs = nb >> 4;
  const int g  = (int)blockIdx.x & 15;
  int a = __hip_atomic_fetch_add(grp_arr + g*64, 1, __ATOMIC_RELAXED, __HIP_MEMORY_SCOPE_AGENT) + 1;
  if (a == ph*gs){
    int r = __hip_atomic_fetch_add(root, 1, __ATOMIC_RELAXED, __HIP_MEMORY_SCOPE_AGENT) + 1;
    if (r == ph*NGRP){
      #pragma unroll
      for (int i = 0; i < NGRP; i++) scsti(grp_gen + i*64, ph);
    }
  }
}
__device__ __forceinline__ void gbar_wait(int* grp_gen, int ph){
  const int g = (int)blockIdx.x & 15;
  while (lcldi(grp_gen + g*64) < ph) __builtin_amdgcn_s_sleep(1);
}
__device__ __forceinline__ void gbarH(int* gA, int* gG, int* gR, int nb, int ph){
  __syncthreads();
  if (threadIdx.x == 0){
    asm volatile("s_waitcnt vmcnt(0) lgkmcnt(0)" ::: "memory");
    gbar_arrive(gA, gG, gR, nb, ph);
    gbar_wait(gG, ph);
  }
  __syncthreads();
}

// ---------- persistent fused encoder: transpose prologue + LDS weights ----------
__global__ __launch_bounds__(512, 1) void enc_scan_kernel(
    const float* __restrict__ demo,    // [T][B][L][D] (slice 0 used)
    const float* __restrict__ Wih, const float* __restrict__ Whh,
    const float* __restrict__ bih, const float* __restrict__ bhh,
    const float* __restrict__ attn_W, const float* __restrict__ attn_b,
    const float* __restrict__ comb_W,
    float* __restrict__ demoT,         // [Ln][Bsz][Dn]  write-once, non-aliased
    float* __restrict__ hencR,         // [Ln][Bsz][Hn]  write-once, non-aliased
    float* __restrict__ attnp,         // [Bsz][Ln][Hn]
    float* __restrict__ CE,            // [Bsz][Ln][Hn] (+pad)
    int* __restrict__ gA, int* __restrict__ gG, int* __restrict__ gR)
{
  const int bid  = blockIdx.x;
  const int tid  = threadIdx.x;
  const int lane = tid & 63;
  const int ks   = tid >> 6;          // 0..7
  const int n0   = bid*2;

  __shared__ float lds_whh[8][Hn];
  __shared__ float lds_wih[8][Dn];
  __shared__ float lds_atw[2][Hn];
  __shared__ float lds_cbw[2][Hn];
  __shared__ float red[8][12][Bsz];

  #pragma unroll
  for (int c = 0; c < 2; c++)
    #pragma unroll
    for (int g = 0; g < 4; g++){
      int r = c*4 + g;
      lds_whh[r][tid] = Whh[(size_t)(g*Hn + n0 + c)*Hn + tid];
      if (tid < Dn) lds_wih[r][tid] = Wih[(size_t)(g*Hn + n0 + c)*Dn + tid];
    }
  #pragma unroll
  for (int c = 0; c < 2; c++){
    lds_atw[c][tid] = attn_W[(size_t)(n0 + c)*Hn + tid];
    lds_cbw[c][tid] = comb_W[(size_t)(n0 + c)*(Hn + Dn) + tid];
  }
  float bsum[2][4];
  #pragma unroll
  for (int c = 0; c < 2; c++)
    #pragma unroll
    for (int g = 0; g < 4; g++){
      int r = g*Hn + n0 + c;
      bsum[c][g] = bih[r] + bhh[r];
    }
  const float ab[2] = { attn_b[n0], attn_b[n0+1] };
  float cr[2] = {0.f, 0.f};
  int pe = 0;

  // ---- prologue: demo transpose (3200 outputs per block) ----
  {
    const int base = bid*3200;
    for (int i = tid; i < 3200; i += 512){
      int idx = base + i;
      int d  = idx & 127;
      int b2 = (idx >> 7) & 63;
      int l2 = idx >> 13;
      scst(demoT + idx, demo[((size_t)(b2*Ln + l2))*Dn + d]);
    }
    gbarH(gA, gG, gR, (int)gridDim.x, ++pe);
  }

  for (int l = 0; l <= Ln; l++){
    float a[2][4] = {{0,0,0,0},{0,0,0,0}};
    float aa[2] = {0,0}, ac[2] = {0,0};
    if (l >= 1){
      const float4* hv = (const float4*)(hencR + ((size_t)(l-1)*Bsz + lane)*Hn) + ks*16;
      #pragma unroll 4
      for (int q = 0; q < 16; q++){
        float4 H = hv[q];
        #pragma unroll
        for (int c = 0; c < 2; c++){
          #pragma unroll
          for (int g = 0; g < 4; g++){
            float4 W = *(const float4*)&lds_whh[c*4+g][ks*64 + 4*q];
            a[c][g] += H.x*W.x + H.y*W.y + H.z*W.z + H.w*W.w;
          }
          float4 Aw = *(const float4*)&lds_atw[c][ks*64 + 4*q];
          aa[c] += H.x*Aw.x + H.y*Aw.y + H.z*Aw.z + H.w*Aw.w;
          float4 Cw = *(const float4*)&lds_cbw[c][ks*64 + 4*q];
          ac[c] += H.x*Cw.x + H.y*Cw.y + H.z*Cw.z + H.w*Cw.w;
        }
      }
    }
    if (l < Ln){
      const float4* dv = (const float4*)(demoT + ((size_t)l*Bsz + lane)*Dn) + ks*4;
      #pragma unroll
      for (int q = 0; q < 4; q++){
        float4 V = dv[q];
        #pragma unroll
        for (int c = 0; c < 2; c++)
          #pragma unroll
          for (int g = 0; g < 4; g++){
            float4 W = *(const float4*)&lds_wih[c*4+g][ks*16 + 4*q];
            a[c][g] += V.x*W.x + V.y*W.y + V.z*W.z + V.w*W.w;
          }
      }
    }
    #pragma unroll
    for (int c = 0; c < 2; c++){
      #pragma unroll
      for (int g = 0; g < 4; g++) red[ks][c*4+g][lane] = a[c][g];
      red[ks][8+c][lane]  = aa[c];
      red[ks][10+c][lane] = ac[c];
    }
    __syncthreads();
    if (tid < Bsz){
      int b = tid;
      if (l < Ln){
        #pragma unroll
        for (int c = 0; c < 2; c++){
          float g0 = bsum[c][0], g1 = bsum[c][1], g2 = bsum[c][2], g3 = bsum[c][3];
          #pragma unroll
          for (int k = 0; k < 8; k++){
            g0 += red[k][c*4+0][b]; g1 += red[k][c*4+1][b];
            g2 += red[k][c*4+2][b]; g3 += red[k][c*4+3][b];
          }
          float ii = sigf(g0), ff = sigf(g1), gg = tanhf(g2), oo = sigf(g3);
          float cn = ff*cr[c] + ii*gg;
          float hn = oo*tanhf(cn);
          cr[c] = cn;
          scst(hencR + ((size_t)l*Bsz + b)*Hn + n0 + c, hn);
        }
      }
      if (l >= 1){
        #pragma unroll
        for (int c = 0; c < 2; c++){
          float av = ab[c], cv = 0.f;
          #pragma unroll
          for (int k = 0; k < 8; k++){ av += red[k][8+c][b]; cv += red[k][10+c][b]; }
          scst(attnp + ((size_t)(b*Ln + (l-1)))*Hn + n0 + c, av);
          scst(CE    + ((size_t)(b*Ln + (l-1)))*Hn + n0 + c, cv);
        }
      }
    }
    if (l < Ln) gbarH(gA, gG, gR, (int)gridDim.x, ++pe);
  }
}

// ---------- persistent decoder: preobs/head-fold prologue, qhead epilogue ----------
__global__ __launch_bounds__(512, 1) void dec_scan_kernel(
    const float* __restrict__ h0, const float* __restrict__ c0,
    const float* __restrict__ state,   // [Tn*Bsz][Dn]
    const float* __restrict__ attnp,   // [Bsz][Ln][Hn]
    const float* __restrict__ CE,      // [Bsz][Ln][Hn] (+pad, over-read x0 safe)
    const int*   __restrict__ dlen,
    const float* __restrict__ lstm_Wih, const float* __restrict__ lstm_Whh,
    const float* __restrict__ lstm_bih, const float* __restrict__ lstm_bhh,
    const float* __restrict__ comb_W,  const float* __restrict__ comb_b,
    const float* __restrict__ mid_W,   const float* __restrict__ mid_b,
    const float* __restrict__ out_W,   const float* __restrict__ out_b,
    float* __restrict__ preobs,        // [Tn*Bsz][Hn]  write-once, non-aliased
    float* __restrict__ M2,            // [An][Hn]      write-once
    float* __restrict__ bias2,         // [An]
    float* __restrict__ xrow,          // [Tn][Bsz][Hn] write-once, non-aliased
    float* __restrict__ hhist,         // [Tn][Bsz][Hn] write-once, non-aliased
    float* __restrict__ outp,
    int* __restrict__ gA, int* __restrict__ gG, int* __restrict__ gR)
{
  const int bid  = blockIdx.x;
  const int tid  = threadIdx.x;
  const int lane = tid & 63;
  const int ks   = tid >> 6;          // 0..7
  const int n0   = bid*2;

  __shared__ float lds_wi[8][Hn];
  __shared__ float lds_wh[8][Hn];
  __shared__ __align__(16) float hs[Hn];
  __shared__ __align__(16) float wls[128];
  __shared__ float mx_s, sum_s;
  __shared__ float red[8][8][Bsz];

  #pragma unroll
  for (int c = 0; c < 2; c++)
    #pragma unroll
    for (int g = 0; g < 4; g++){
      int r = c*4 + g;
      lds_wi[r][tid] = lstm_Wih[(size_t)(g*Hn + n0 + c)*Hn + tid];
      lds_wh[r][tid] = lstm_Whh[(size_t)(g*Hn + n0 + c)*Hn + tid];
    }
  float bs[2][4];
  #pragma unroll
  for (int c = 0; c < 2; c++)
    #pragma unroll
    for (int g = 0; g < 4; g++){
      int r = g*Hn + n0 + c;
      bs[c][g] = lstm_bih[r] + lstm_bhh[r];
    }
  float cr[2] = {0.f, 0.f};
  int len = 0, lenr = 0;
  if (bid < Bsz){ len = dlen[bid]; lenr = (len + 7) & ~7; }
  int ph = 0;

  // ---- prologue: preobs cols n0,n0+1 (all blocks, ALL 4096 rows) + head fold ----
  {
    if (tid < Dn){
      hs[tid]      = comb_W[(size_t)n0*(Hn+Dn)     + Hn + tid];
      hs[Dn + tid] = comb_W[(size_t)(n0+1)*(Hn+Dn) + Hn + tid];
    }
    __syncthreads();
    #pragma unroll
    for (int p = 0; p < 8; p++){
      int r = p*512 + tid;          // 0..4095
      const float4* sv = (const float4*)(state + (size_t)r*Dn);
      const float4* w0 = (const float4*)hs;
      const float4* w1 = (const float4*)(hs + Dn);
      float a0 = 0.f, a1 = 0.f;
      #pragma unroll 8
      for (int q = 0; q < 32; q++){
        float4 S = sv[q], W0 = w0[q], W1 = w1[q];
        a0 += S.x*W0.x + S.y*W0.y + S.z*W0.z + S.w*W0.w;
        a1 += S.x*W1.x + S.y*W1.y + S.z*W1.z + S.w*W1.w;
      }
      scst(preobs + (size_t)r*Hn + n0,     a0);
      scst(preobs + (size_t)r*Hn + n0 + 1, a1);
    }
    if (bid < An){
      const float* ow = out_W + (size_t)bid*Hn;
      float s = 0.f;
      #pragma unroll 4
      for (int n = 0; n < Hn; n++) s += ow[n]*mid_W[(size_t)n*Hn + tid];
      scst(M2 + (size_t)bid*Hn + tid, s);
      if (tid == 0){
        float b2 = out_b[bid];
        for (int n = 0; n < Hn; n++) b2 += ow[n]*mid_b[n];
        scst(bias2 + bid, b2);
      }
    }
    gbarH(gA, gG, gR, (int)gridDim.x, ++ph);
  }

  for (int t = 0; t < Tn; t++){
    const float* hprev_all = (t == 0) ? h0 : (hhist + (size_t)(t-1)*Bsz*Hn);

    // ============ Phase 1: attention (blocks 0..63) + Whh@h partial (ALL) ============
    if (bid < Bsz){
      const int b = bid;
      hs[tid] = hprev_all[(size_t)b*Hn + tid];
      if (tid >= 100 && tid < 128) wls[tid] = -1e30f;
      __syncthreads();
      if (tid < 400){
        int l = tid >> 2, kh = tid & 3;
        const float4* ap = (const float4*)(attnp + ((size_t)(b*Ln + l))*Hn) + kh*32;
        const float4* hv = (const float4*)hs + kh*32;
        float s = 0.f;
        #pragma unroll 8
        for (int k = 0; k < 32; k++){
          float4 A = ap[k], H = hv[k];
          s += A.x*H.x + A.y*H.y + A.z*H.z + A.w*H.w;
        }
        s += __shfl_xor(s, 1);
        s += __shfl_xor(s, 2);
        if (kh == 0) wls[l] = (l < len) ? s*0.1f : -1e30f;
      }
      __syncthreads();
      if (tid < 64){
        float v = fmaxf(wls[tid], wls[tid+64]);
        for (int off = 1; off < 64; off <<= 1) v = fmaxf(v, __shfl_xor(v, off));
        if (tid == 0) mx_s = v;
      }
      __syncthreads();
      float mx = mx_s;
      if (tid < 64){
        float e0 = (wls[tid]    > -1e29f) ? expf(wls[tid]    - mx) : 0.f;
        float e1 = (wls[tid+64] > -1e29f) ? expf(wls[tid+64] - mx) : 0.f;
        wls[tid] = e0; wls[tid+64] = e1;   // exact 0.0 beyond len (incl. 100..127)
        float v = e0 + e1;
        for (int off = 1; off < 64; off <<= 1) v += __shfl_xor(v, off);
        if (tid == 0) sum_s = v;
      }
      __syncthreads();
      float inv = 1.0f / sum_s;
      {
        int n = tid;
        const float* cb = CE + (size_t)b*Ln*Hn + n;
        float acc = 0.f;
        #pragma unroll 8
        for (int l2 = 0; l2 < lenr; ++l2) acc += cb[(size_t)l2*Hn]*wls[l2]; // wls==0 pads
        float v = acc*inv + preobs[((size_t)(t*Bsz + b))*Hn + n] + comb_b[n];
        scst(xrow + ((size_t)t*Bsz + b)*Hn + n, fmaxf(v, 0.f));
      }
    }
    // all blocks: Whh @ h(t-1) partial for own 2 columns; kept in VGPRs across barrier
    float hpa[2][4] = {{0,0,0,0},{0,0,0,0}};
    {
      const float4* hv = (const float4*)(hprev_all + (size_t)lane*Hn) + ks*16;
      #pragma unroll 4
      for (int q = 0; q < 16; q++){
        float4 H = hv[q];
        #pragma unroll
        for (int c = 0; c < 2; c++)
          #pragma unroll
          for (int g = 0; g < 4; g++){
            float4 W = *(const float4*)&lds_wh[c*4+g][ks*64 + 4*q];
            hpa[c][g] += H.x*W.x + H.y*W.y + H.z*W.z + H.w*W.w;
          }
      }
    }
    gbarH(gA, gG, gR, (int)gridDim.x, ++ph);

    // ============ Phase 2: += Wih@x; reduce; cell ============
    {
      const float4* xv = (const float4*)(xrow + ((size_t)t*Bsz + lane)*Hn) + ks*16;
      #pragma unroll 4
      for (int q = 0; q < 16; q++){
        float4 X = xv[q];
        #pragma unroll
        for (int c = 0; c < 2; c++)
          #pragma unroll
          for (int g = 0; g < 4; g++){
            float4 W = *(const float4*)&lds_wi[c*4+g][ks*64 + 4*q];
            hpa[c][g] += X.x*W.x + X.y*W.y + X.z*W.z + X.w*W.w;
          }
      }
      #pragma unroll
      for (int c = 0; c < 2; c++)
        #pragma unroll
        for (int g = 0; g < 4; g++) red[ks][c*4+g][lane] = hpa[c][g];
      __syncthreads();
      if (tid < Bsz){
        int b = tid;
        #pragma unroll
        for (int c = 0; c < 2; c++){
          int n = n0 + c;
          if (t == 0) cr[c] = c0[(size_t)b*Hn + n];
          float g0 = bs[c][0], g1 = bs[c][1], g2 = bs[c][2], g3 = bs[c][3];
          #pragma unroll
          for (int k = 0; k < 8; k++){
            g0 += red[k][c*4+0][b]; g1 += red[k][c*4+1][b];
            g2 += red[k][c*4+2][b]; g3 += red[k][c*4+3][b];
          }
          float ii = sigf(g0), ff = sigf(g1), gg = tanhf(g2), oo = sigf(g3);
          float cn = ff*cr[c] + ii*gg;
          float hn = oo*tanhf(cn);
          cr[c] = cn;
          scst(hhist + ((size_t)t*Bsz + b)*Hn + n, hn);
          if (t == Tn - 1){
            outp[Tn*Bsz*An + (size_t)b*Hn + n]           = hn;
            outp[Tn*Bsz*An + Bsz*Hn + (size_t)b*Hn + n]  = cn;
          }
        }
      }
    }
    gbarH(gA, gG, gR, (int)gridDim.x, ++ph);   // last-step barrier feeds epilogue
  }

  // ---- epilogue: q[t][b][a] = hhist[t][b].M2[a] + bias2[a] ----
  {
    const int tq = bid & 63;
    const int qd = bid >> 6;          // 0..3
    for (int j = 0; j < 36; j++){
      int oi = qd*288 + ks*36 + j;    // 0..1151
      int b = oi / An, a = oi % An;
      const float4* hv = (const float4*)(hhist + ((size_t)tq*Bsz + b)*Hn) + lane*2;
      const float4* mv = (const float4*)(M2 + (size_t)a*Hn) + lane*2;
      float4 H0 = hv[0], H1 = hv[1], M0 = mv[0], M1 = mv[1];
      float s = H0.x*M0.x + H0.y*M0.y + H0.z*M0.z + H0.w*M0.w
              + H1.x*M1.x + H1.y*M1.y + H1.z*M1.z + H1.w*M1.w;
      #pragma unroll
      for (int off = 1; off < 64; off <<= 1) s += __shfl_xor(s, off);
      if (lane == 0) outp[((size_t)tq*Bsz + b)*An + a] = s + bias2[a];
    }
  }
}

extern "C" void kernel_launch(void* const* d_in, const int* in_sizes, int n_in,
                              void* d_out, int out_size, void* d_ws, size_t ws_size,
                              hipStream_t stream) {
  (void)in_sizes; (void)n_in; (void)out_size; (void)ws_size;
  const float* state    = (const float*)d_in[0];
  const float* demo     = (const float*)d_in[1];
  const int*   dlen     = (const int*)  d_in[2];
  const float* h0       = (const float*)d_in[5];
  const float* c0       = (const float*)d_in[6];
  const float* enc_Wih  = (const float*)d_in[7];
  const float* enc_Whh  = (const float*)d_in[8];
  const float* enc_bih  = (const float*)d_in[9];
  const float* enc_bhh  = (const float*)d_in[10];
  const float* attn_W   = (const float*)d_in[11];
  const float* attn_b   = (const float*)d_in[12];
  const float* comb_W   = (const float*)d_in[13];
  const float* comb_b   = (const float*)d_in[14];
  const float* lstm_Wih = (const float*)d_in[15];
  const float* lstm_Whh = (const float*)d_in[16];
  const float* lstm_bih = (const float*)d_in[17];
  const float* lstm_bhh = (const float*)d_in[18];
  const float* mid_W    = (const float*)d_in[19];
  const float* mid_b    = (const float*)d_in[20];
  const float* out_W    = (const float*)d_in[21];
  const float* out_b    = (const float*)d_in[22];
  float* ws   = (float*)d_ws;
  float* qout = (float*)d_out;

  // NON-ALIASED workspace layout (f32 words) — ~64.7 MiB total.
  float* attnp  = ws + 0;          // 3,276,800   [B][L][H]
  float* CE     = ws + 3276800;    // 3,276,800 + 2048 pad (lenr over-read)
  float* preobs = ws + 6555648;    // 2,097,152   [T*B][H]
  float* demoT  = ws + 8652800;    //   819,200   [L][B][D]
  float* hencR  = ws + 9472000;    // 3,276,800   [L][B][H]
  float* xrow   = ws + 12748800;   // 2,097,152   [T][B][H]
  float* hhist  = ws + 14845952;   // 2,097,152   [T][B][H]
  int*   barB   = (int*)(ws + 16943104);  // 4,224 ints
  int* encA = barB;          int* encG = barB + 1024; int* encR = barB + 2048;
  int* decA = barB + 2112;   int* decG = barB + 3136; int* decR = barB + 4160;
  float* M2    = ws + 16947328;    // 9,216  [An][Hn]
  float* bias2 = ws + 16956544;    // 64

  hipMemsetAsync((void*)barB, 0, 4224*4, stream);

  enc_scan_kernel<<<256, 512, 0, stream>>>(
      demo, enc_Wih, enc_Whh, enc_bih, enc_bhh, attn_W, attn_b, comb_W,
      demoT, hencR, attnp, CE, encA, encG, encR);

  dec_scan_kernel<<<256, 512, 0, stream>>>(
      h0, c0, state, attnp, CE, dlen, lstm_Wih, lstm_Whh, lstm_bih, lstm_bhh,
      comb_W, comb_b, mid_W, mid_b, out_W, out_b,
      preobs, M2, bias2, xrow, hhist, qout, decA, decG, decR);
}